// Round 3
// baseline (3685.476 us; speedup 1.0000x reference)
//
#include <hip/hip_runtime.h>

typedef unsigned short u16;
typedef unsigned int u32;
typedef unsigned long long u64;

#define NPB 8192
#define BCL 4
#define MS 2048
#define KN 64
#define OFF_POS   (BCL * MS * 128)            // 1048576 elements
#define OFF_BATCH (OFF_POS + BCL * MS * 3)    // 1073152 elements

__device__ inline float bf2f(u16 v) { return __uint_as_float(((u32)v) << 16); }
__device__ inline u16 f2bf(float f) {
  u32 u = __float_as_uint(f);
  u += 0x7fffu + ((u >> 16) & 1u);
  return (u16)(u >> 16);
}
// element-indexed dual-dtype access (p is the raw buffer base)
__device__ inline float ldf(const u16* p, size_t i, bool f32) {
  return f32 ? ((const float*)p)[i] : bf2f(p[i]);
}
__device__ inline void stf(u16* p, size_t i, float v, bool f32) {
  if (f32) ((float*)p)[i] = v; else p[i] = f2bf(v);
}
__device__ inline void cpe(u16* d, size_t j, const u16* s, size_t i, bool f32) {
  if (f32) ((float*)d)[j] = ((const float*)s)[i]; else d[j] = s[i];
}

// dtype sniffer: pos ~ uniform[0,1). bf16 buffer -> all u16s decode into [0,1).
// f32 buffer -> even u16s are mantissa-low garbage, ~75% decode outside [0,1).
__device__ inline bool sniff_f32(const u16* pos) {
  int bad = 0;
  for (int i = 0; i < 32; ++i) {
    float f = bf2f(pos[i]);
    if (!(f >= 0.0f && f < 1.0f)) ++bad;
  }
  return bad >= 4;
}

// ---------------------------------------------------------------------------
// Kernel 1: farthest point sampling, one block/cloud, coords in registers.
// Exact f32 arithmetic (no fma), np argmax tie-break (first index).
// ---------------------------------------------------------------------------
__global__ __launch_bounds__(1024) void fps_kernel(
    const u16* __restrict__ pos, int* __restrict__ samp, u16* __restrict__ out) {
  const bool F32 = sniff_f32(pos);
  int b = blockIdx.x, t = threadIdx.x, lane = t & 63, wv = t >> 6;
  size_t base = (size_t)b * NPB * 3;

  __shared__ int s_samp[MS];
  __shared__ u64 red[16];
  __shared__ float s_bc[3];

  float px[8], py[8], pz[8], mind[8];
  for (int i = 0; i < 8; ++i) {
    size_t p = base + (size_t)(t + i * 1024) * 3;
    px[i] = ldf(pos, p, F32);
    py[i] = ldf(pos, p + 1, F32);
    pz[i] = ldf(pos, p + 2, F32);
  }
  float fx = ldf(pos, base, F32), fy = ldf(pos, base + 1, F32), fz = ldf(pos, base + 2, F32);
  for (int i = 0; i < 8; ++i) {
    float dx = __fsub_rn(px[i], fx), dy = __fsub_rn(py[i], fy), dz = __fsub_rn(pz[i], fz);
    mind[i] = __fadd_rn(__fadd_rn(__fmul_rn(dx, dx), __fmul_rn(dy, dy)), __fmul_rn(dz, dz));
  }
  if (t == 0) s_samp[0] = 0;

  for (int it = 1; it < MS; ++it) {
    // key = (d2 bits << 32) | ~idx : max -> largest d2, ties -> smallest idx
    u64 best = 0;
    for (int i = 0; i < 8; ++i) {
      u64 key = ((u64)__float_as_uint(mind[i]) << 32) | (u32)(~(u32)(t + i * 1024));
      best = best < key ? key : best;
    }
    for (int o = 32; o > 0; o >>= 1) {
      u64 oth = __shfl_xor(best, o, 64);
      best = best < oth ? oth : best;
    }
    if (lane == 0) red[wv] = best;
    __syncthreads();
    u64 g = red[0];
    for (int k = 1; k < 16; ++k) { u64 o = red[k]; g = g < o ? o : g; }
    int win = (int)(~(u32)g) & (NPB - 1);
    if (t == 0) s_samp[it] = win;
    if (t == (win & 1023)) {       // owner broadcasts winner coords
      int i = win >> 10;
      s_bc[0] = px[i]; s_bc[1] = py[i]; s_bc[2] = pz[i];
    }
    __syncthreads();
    fx = s_bc[0]; fy = s_bc[1]; fz = s_bc[2];
    for (int i = 0; i < 8; ++i) {
      float dx = __fsub_rn(px[i], fx), dy = __fsub_rn(py[i], fy), dz = __fsub_rn(pz[i], fz);
      float d = __fadd_rn(__fadd_rn(__fmul_rn(dx, dx), __fmul_rn(dy, dy)), __fmul_rn(dz, dz));
      mind[i] = fminf(mind[i], d);
    }
  }
  __syncthreads();
  for (int m = t; m < MS; m += 1024) {
    int s = s_samp[m];
    int g = b * MS + m;
    samp[g] = s;
    for (int d = 0; d < 3; ++d)
      cpe(out, OFF_POS + (size_t)g * 3 + d, pos, base + (size_t)s * 3 + d, F32);
    stf(out, OFF_BATCH + g, (float)b, F32);
  }
}

// ---------------------------------------------------------------------------
// Kernel 2: radius ball + K-nearest-in-ball (lax.top_k semantics).
// ---------------------------------------------------------------------------
__global__ __launch_bounds__(256) void nbr_kernel(
    const u16* __restrict__ pos, const int* __restrict__ samp,
    int* __restrict__ nbr) {
  const float R2CUT = (float)(0.2 * 0.2);   // 0x3D23D70A: matches np f64 cmp & jnp f32
  const bool F32 = sniff_f32(pos);
  int c = blockIdx.x, b = c >> 11, t = threadIdx.x;
  size_t base = (size_t)b * NPB * 3;
  int s = samp[c] & (NPB - 1);
  float cx = ldf(pos, base + (size_t)s * 3, F32);
  float cy = ldf(pos, base + (size_t)s * 3 + 1, F32);
  float cz = ldf(pos, base + (size_t)s * 3 + 2, F32);
  __shared__ u64 cand[512];
  __shared__ int cnt;
  if (t == 0) cnt = 0;
  __syncthreads();
  for (int j = t; j < NPB; j += 256) {
    float dx = __fsub_rn(ldf(pos, base + (size_t)j * 3, F32), cx);
    float dy = __fsub_rn(ldf(pos, base + (size_t)j * 3 + 1, F32), cy);
    float dz = __fsub_rn(ldf(pos, base + (size_t)j * 3 + 2, F32), cz);
    float d2 = __fadd_rn(__fadd_rn(__fmul_rn(dx, dx), __fmul_rn(dy, dy)), __fmul_rn(dz, dz));
    if (d2 <= R2CUT) {
      int sl = atomicAdd(&cnt, 1);
      if (sl < 512) cand[sl] = ((u64)__float_as_uint(d2) << 32) | (u32)j;
    }
  }
  __syncthreads();
  int n = cnt; if (n > 512) n = 512;        // mean in-ball ~274; overflow ~impossible
  for (int i = t; i < 512; i += 256) if (i >= n) cand[i] = ~0ull;
  __syncthreads();
  for (int k = 2; k <= 512; k <<= 1) {
    for (int j = k >> 1; j > 0; j >>= 1) {
      for (int i = t; i < 512; i += 256) {
        int ix = i ^ j;
        if (ix > i) {
          u64 a = cand[i], bb = cand[ix];
          bool up = ((i & k) == 0);
          if ((a > bb) == up) { cand[i] = bb; cand[ix] = a; }
        }
      }
      __syncthreads();
    }
  }
  if (t < KN) nbr[(size_t)c * KN + t] = (t < n) ? (int)(cand[t] & 0xffffffffu) : -1;
}

// ---------------------------------------------------------------------------
// Kernel 3: gather -> f32 VALU MLP (67->64->64->128, relu) -> masked max-pool.
// One center (64 neighbor rows) per 256-thread block.
// ---------------------------------------------------------------------------
__global__ __launch_bounds__(256) void mlp_kernel(
    const u16* __restrict__ x, const u16* __restrict__ pos,
    const int* __restrict__ samp, const int* __restrict__ nbr,
    const u16* __restrict__ W1, const u16* __restrict__ b1,
    const u16* __restrict__ W2, const u16* __restrict__ b2,
    const u16* __restrict__ W3, const u16* __restrict__ b3,
    u16* __restrict__ out) {
  const bool F32 = sniff_f32(pos);
  int c = blockIdx.x, b = c >> 11, t = threadIdx.x;

  __shared__ float s_feat[64][68];   // feat (67 cols); reused as h2 (64 cols)
  __shared__ float s_h[64][68];      // h1
  __shared__ float s_w[68][64];      // staged weights [k][n]
  __shared__ float s_mask[64];
  __shared__ float s_red[4][64];

  const int* nb = nbr + (size_t)c * KN;

  // ---- gather x features ----
  {
    int r = t >> 2, q = t & 3;
    int j = nb[r];
    bool valid = (j >= 0 && j < NPB);
    size_t jj = valid ? (size_t)j : 0;
    for (int i = 0; i < 16; ++i) {
      float v = ldf(x, ((size_t)b * NPB + jj) * 64 + q * 16 + i, F32);
      s_feat[r][q * 16 + i] = valid ? v : 0.0f;
    }
  }
  // ---- posdiff + validity mask ----
  if (t < 64) {
    int r = t;
    int j = nb[r];
    bool valid = (j >= 0 && j < NPB);
    s_mask[r] = valid ? 0.0f : -__builtin_inff();
    int s = samp[c] & (NPB - 1);
    size_t jj = valid ? (size_t)j : (size_t)s;
    for (int d = 0; d < 3; ++d) {
      float pj = ldf(pos, ((size_t)b * NPB + jj) * 3 + d, F32);
      float pc = ldf(pos, ((size_t)b * NPB + s) * 3 + d, F32);
      s_feat[r][64 + d] = __fsub_rn(pj, pc);
    }
  }
  // ---- stage W1 [67][64] ----
  for (int idx = t; idx < 67 * 64; idx += 256)
    s_w[idx >> 6][idx & 63] = ldf(W1, idx, F32);
  __syncthreads();

  // ---- layer 1 ----
  {
    int r = t >> 2, n0 = (t & 3) * 16;
    float acc[16];
    for (int j = 0; j < 16; ++j) acc[j] = ldf(b1, n0 + j, F32);
    for (int k = 0; k < 67; ++k) {
      float f = s_feat[r][k];
      for (int j = 0; j < 16; ++j) acc[j] += f * s_w[k][n0 + j];
    }
    __syncthreads();               // all W1 reads done before restage
    for (int j = 0; j < 16; ++j) s_h[r][n0 + j] = fmaxf(acc[j], 0.0f);
  }
  // ---- stage W2 [64][64] ----
  for (int idx = t; idx < 64 * 64; idx += 256)
    s_w[idx >> 6][idx & 63] = ldf(W2, idx, F32);
  __syncthreads();

  // ---- layer 2 (h2 overwrites s_feat) ----
  {
    int r = t >> 2, n0 = (t & 3) * 16;
    float acc[16];
    for (int j = 0; j < 16; ++j) acc[j] = ldf(b2, n0 + j, F32);
    for (int k = 0; k < 64; ++k) {
      float f = s_h[r][k];
      for (int j = 0; j < 16; ++j) acc[j] += f * s_w[k][n0 + j];
    }
    __syncthreads();               // all W2 + s_feat reads done
    for (int j = 0; j < 16; ++j) s_feat[r][n0 + j] = fmaxf(acc[j], 0.0f);
  }
  __syncthreads();

  // ---- layer 3, two 64-col halves, fused masked max-pool ----
  for (int h = 0; h < 2; ++h) {
    for (int idx = t; idx < 64 * 64; idx += 256)
      s_w[idx >> 6][idx & 63] = ldf(W3, (size_t)(idx >> 6) * 128 + h * 64 + (idx & 63), F32);
    __syncthreads();
    int n = t & 63, rg = t >> 6;
    float acc[16];
    float bias = ldf(b3, h * 64 + n, F32);
    for (int rr = 0; rr < 16; ++rr) acc[rr] = bias;
    for (int k = 0; k < 64; ++k) {
      float w = s_w[k][n];
      for (int rr = 0; rr < 16; ++rr) acc[rr] += s_feat[rg * 16 + rr][k] * w;
    }
    float m = -__builtin_inff();
    for (int rr = 0; rr < 16; ++rr)
      m = fmaxf(m, fmaxf(acc[rr], 0.0f) + s_mask[rg * 16 + rr]);
    s_red[rg][n] = m;
    __syncthreads();
    if (t < 64) {
      float mm = fmaxf(fmaxf(s_red[0][t], s_red[1][t]), fmaxf(s_red[2][t], s_red[3][t]));
      stf(out, (size_t)c * 128 + h * 64 + t, mm, F32);
    }
    __syncthreads();               // protect s_w restage for h=1
  }
}

// ---------------------------------------------------------------------------
extern "C" void kernel_launch(void* const* d_in, const int* in_sizes, int n_in,
                              void* d_out, int out_size, void* d_ws, size_t ws_size,
                              hipStream_t stream) {
  const u16* x   = (const u16*)d_in[0];
  const u16* pos = (const u16*)d_in[1];
  // d_in[2] = batch (int32), unused
  const u16* W1 = (const u16*)d_in[3];
  const u16* b1 = (const u16*)d_in[4];
  const u16* W2 = (const u16*)d_in[5];
  const u16* b2 = (const u16*)d_in[6];
  const u16* W3 = (const u16*)d_in[7];
  const u16* b3 = (const u16*)d_in[8];

  u16* out = (u16*)d_out;            // element-indexed via helpers (f32 or bf16)
  int* samp = (int*)d_ws;            // [8192]
  int* nbr = samp + BCL * MS;        // [8192*64]

  fps_kernel<<<BCL, 1024, 0, stream>>>(pos, samp, out);
  nbr_kernel<<<BCL * MS, 256, 0, stream>>>(pos, samp, nbr);
  mlp_kernel<<<BCL * MS, 256, 0, stream>>>(x, pos, samp, nbr,
                                           W1, b1, W2, b2, W3, b3, out);
}

// Round 4
// 3247.223 us; speedup vs baseline: 1.1350x; 1.1350x over previous
//
#include <hip/hip_runtime.h>

typedef unsigned short u16;
typedef unsigned int u32;
typedef unsigned long long u64;

#define NPB 8192
#define BCL 4
#define MS 2048
#define KN 64
#define OFF_POS   (BCL * MS * 128)            // element offsets into d_out (f32)
#define OFF_BATCH (OFF_POS + BCL * MS * 3)

__device__ inline u64 umax64(u64 a, u64 b) { return a < b ? b : a; }

// ---------------------------------------------------------------------------
// Kernel 1: farthest point sampling, one block/cloud, 1024 thr, 8 pts/thread.
// Exact f32 arithmetic (no fma), np argmax tie-break (first index).
// Single barrier per iteration: double-buffered reduction slots, winner
// coords re-read from global (uniform L2 broadcast) instead of LDS broadcast.
// ---------------------------------------------------------------------------
__global__ __launch_bounds__(1024) void fps_kernel(
    const float* __restrict__ pos, int* __restrict__ samp,
    float* __restrict__ out) {
  int b = blockIdx.x, t = threadIdx.x, lane = t & 63, wv = t >> 6;
  const float* pb = pos + (size_t)b * NPB * 3;

  __shared__ u64 red[2][16];

  float px[8], py[8], pz[8], mind[8];
  for (int i = 0; i < 8; ++i) {
    int p = t + i * 1024;
    px[i] = pb[p * 3]; py[i] = pb[p * 3 + 1]; pz[i] = pb[p * 3 + 2];
  }
  float cx = pb[0], cy = pb[1], cz = pb[2];
  for (int i = 0; i < 8; ++i) {
    float dx = __fsub_rn(px[i], cx), dy = __fsub_rn(py[i], cy), dz = __fsub_rn(pz[i], cz);
    mind[i] = __fadd_rn(__fadd_rn(__fmul_rn(dx, dx), __fmul_rn(dy, dy)), __fmul_rn(dz, dz));
  }

  float* pos_out = out + OFF_POS + (size_t)b * MS * 3;
  float* batch_out = out + OFF_BATCH + (size_t)b * MS;
  if (t == 0) {
    samp[b * MS] = 0;
    pos_out[0] = cx; pos_out[1] = cy; pos_out[2] = cz;
  }

  for (int it = 1; it < MS; ++it) {
    // local argmax over 8 pts, tree-shaped.
    // key = (d2 bits << 32) | ~idx : max -> largest d2, ties -> smallest idx
    u64 k0, k1, k2, k3, k4, k5, k6, k7;
    k0 = ((u64)__float_as_uint(mind[0]) << 32) | (u32)(~(u32)(t));
    k1 = ((u64)__float_as_uint(mind[1]) << 32) | (u32)(~(u32)(t + 1024));
    k2 = ((u64)__float_as_uint(mind[2]) << 32) | (u32)(~(u32)(t + 2048));
    k3 = ((u64)__float_as_uint(mind[3]) << 32) | (u32)(~(u32)(t + 3072));
    k4 = ((u64)__float_as_uint(mind[4]) << 32) | (u32)(~(u32)(t + 4096));
    k5 = ((u64)__float_as_uint(mind[5]) << 32) | (u32)(~(u32)(t + 5120));
    k6 = ((u64)__float_as_uint(mind[6]) << 32) | (u32)(~(u32)(t + 6144));
    k7 = ((u64)__float_as_uint(mind[7]) << 32) | (u32)(~(u32)(t + 7168));
    k0 = umax64(k0, k1); k2 = umax64(k2, k3); k4 = umax64(k4, k5); k6 = umax64(k6, k7);
    k0 = umax64(k0, k2); k4 = umax64(k4, k6);
    u64 best = umax64(k0, k4);
    // wave butterfly (64 lanes)
    for (int o = 32; o > 0; o >>= 1) {
      u64 oth = __shfl_xor(best, o, 64);
      best = umax64(best, oth);
    }
    if (lane == 0) red[it & 1][wv] = best;
    __syncthreads();
    // tree-scan the 16 wave maxima (broadcast reads, no conflicts)
    const u64* rr = red[it & 1];
    u64 a0 = umax64(umax64(rr[0], rr[1]), umax64(rr[2], rr[3]));
    u64 a1 = umax64(umax64(rr[4], rr[5]), umax64(rr[6], rr[7]));
    u64 a2 = umax64(umax64(rr[8], rr[9]), umax64(rr[10], rr[11]));
    u64 a3 = umax64(umax64(rr[12], rr[13]), umax64(rr[14], rr[15]));
    u64 g = umax64(umax64(a0, a1), umax64(a2, a3));
    int win = (int)(~(u32)g) & (NPB - 1);
    // winner coords: uniform global load (L2-resident, 96 KB cloud)
    cx = pb[win * 3]; cy = pb[win * 3 + 1]; cz = pb[win * 3 + 2];
    if (t == 0) {
      samp[b * MS + it] = win;
      pos_out[it * 3] = cx; pos_out[it * 3 + 1] = cy; pos_out[it * 3 + 2] = cz;
    }
    for (int i = 0; i < 8; ++i) {
      float dx = __fsub_rn(px[i], cx), dy = __fsub_rn(py[i], cy), dz = __fsub_rn(pz[i], cz);
      float d = __fadd_rn(__fadd_rn(__fmul_rn(dx, dx), __fmul_rn(dy, dy)), __fmul_rn(dz, dz));
      mind[i] = fminf(mind[i], d);
    }
  }
  for (int m = t; m < MS; m += 1024) batch_out[m] = (float)b;
}

// ---------------------------------------------------------------------------
// Kernel 2: radius ball + K-nearest-in-ball (lax.top_k semantics).
// ---------------------------------------------------------------------------
__global__ __launch_bounds__(256) void nbr_kernel(
    const float* __restrict__ pos, const int* __restrict__ samp,
    int* __restrict__ nbr) {
  const float R2CUT = (float)(0.2 * 0.2);   // 0x3D23D70A
  int c = blockIdx.x, b = c >> 11, t = threadIdx.x;
  const float* pb = pos + (size_t)b * NPB * 3;
  int s = samp[c] & (NPB - 1);
  float cx = pb[s * 3], cy = pb[s * 3 + 1], cz = pb[s * 3 + 2];
  __shared__ u64 cand[512];
  __shared__ int cnt;
  if (t == 0) cnt = 0;
  __syncthreads();
  for (int j = t; j < NPB; j += 256) {
    float dx = __fsub_rn(pb[j * 3], cx);
    float dy = __fsub_rn(pb[j * 3 + 1], cy);
    float dz = __fsub_rn(pb[j * 3 + 2], cz);
    float d2 = __fadd_rn(__fadd_rn(__fmul_rn(dx, dx), __fmul_rn(dy, dy)), __fmul_rn(dz, dz));
    if (d2 <= R2CUT) {
      int sl = atomicAdd(&cnt, 1);
      if (sl < 512) cand[sl] = ((u64)__float_as_uint(d2) << 32) | (u32)j;
    }
  }
  __syncthreads();
  int n = cnt; if (n > 512) n = 512;        // mean in-ball ~274; overflow ~impossible
  for (int i = t; i < 512; i += 256) if (i >= n) cand[i] = ~0ull;
  __syncthreads();
  for (int k = 2; k <= 512; k <<= 1) {
    for (int j = k >> 1; j > 0; j >>= 1) {
      for (int i = t; i < 512; i += 256) {
        int ix = i ^ j;
        if (ix > i) {
          u64 a = cand[i], bb = cand[ix];
          bool up = ((i & k) == 0);
          if ((a > bb) == up) { cand[i] = bb; cand[ix] = a; }
        }
      }
      __syncthreads();
    }
  }
  if (t < KN) nbr[(size_t)c * KN + t] = (t < n) ? (int)(cand[t] & 0xffffffffu) : -1;
}

// ---------------------------------------------------------------------------
// Kernel 3: gather -> f32 VALU MLP (67->64->64->128, relu) -> masked max-pool.
// One center (64 neighbor rows) per 256-thread block. Arithmetic order is
// bit-exact vs R3 (absmax 0.0) — do not reorder sums.
// ---------------------------------------------------------------------------
__global__ __launch_bounds__(256) void mlp_kernel(
    const float* __restrict__ x, const float* __restrict__ pos,
    const int* __restrict__ samp, const int* __restrict__ nbr,
    const float* __restrict__ W1, const float* __restrict__ b1,
    const float* __restrict__ W2, const float* __restrict__ b2,
    const float* __restrict__ W3, const float* __restrict__ b3,
    float* __restrict__ out) {
  int c = blockIdx.x, b = c >> 11, t = threadIdx.x;

  __shared__ float s_feat[64][68];   // feat (67 cols); reused as h2 (64 cols)
  __shared__ float s_h[64][68];      // h1
  __shared__ float s_w[68][64];      // staged weights [k][n]
  __shared__ float s_mask[64];
  __shared__ float s_red[4][64];

  const int* nb = nbr + (size_t)c * KN;

  // ---- gather x features (float4-vectorized) ----
  {
    int r = t >> 2, q = t & 3;
    int j = nb[r];
    bool valid = (j >= 0 && j < NPB);
    size_t jj = valid ? (size_t)j : 0;
    const float4* xp = (const float4*)(x + ((size_t)b * NPB + jj) * 64 + q * 16);
    float4 v[4];
    for (int i = 0; i < 4; ++i) v[i] = xp[i];
    for (int i = 0; i < 4; ++i) {
      s_feat[r][q * 16 + i * 4 + 0] = valid ? v[i].x : 0.0f;
      s_feat[r][q * 16 + i * 4 + 1] = valid ? v[i].y : 0.0f;
      s_feat[r][q * 16 + i * 4 + 2] = valid ? v[i].z : 0.0f;
      s_feat[r][q * 16 + i * 4 + 3] = valid ? v[i].w : 0.0f;
    }
  }
  // ---- posdiff + validity mask ----
  if (t < 64) {
    int r = t;
    int j = nb[r];
    bool valid = (j >= 0 && j < NPB);
    s_mask[r] = valid ? 0.0f : -__builtin_inff();
    int s = samp[c] & (NPB - 1);
    size_t jj = valid ? (size_t)j : (size_t)s;
    for (int d = 0; d < 3; ++d) {
      float pj = pos[((size_t)b * NPB + jj) * 3 + d];
      float pc = pos[((size_t)b * NPB + s) * 3 + d];
      s_feat[r][64 + d] = __fsub_rn(pj, pc);
    }
  }
  // ---- stage W1 [67][64] ----
  for (int idx = t; idx < 67 * 64; idx += 256)
    s_w[idx >> 6][idx & 63] = W1[idx];
  __syncthreads();

  // ---- layer 1 ----
  {
    int r = t >> 2, n0 = (t & 3) * 16;
    float acc[16];
    for (int j = 0; j < 16; ++j) acc[j] = b1[n0 + j];
    for (int k = 0; k < 67; ++k) {
      float f = s_feat[r][k];
      for (int j = 0; j < 16; ++j) acc[j] += f * s_w[k][n0 + j];
    }
    __syncthreads();               // all W1 reads done before restage
    for (int j = 0; j < 16; ++j) s_h[r][n0 + j] = fmaxf(acc[j], 0.0f);
  }
  // ---- stage W2 [64][64] ----
  for (int idx = t; idx < 64 * 64; idx += 256)
    s_w[idx >> 6][idx & 63] = W2[idx];
  __syncthreads();

  // ---- layer 2 (h2 overwrites s_feat) ----
  {
    int r = t >> 2, n0 = (t & 3) * 16;
    float acc[16];
    for (int j = 0; j < 16; ++j) acc[j] = b2[n0 + j];
    for (int k = 0; k < 64; ++k) {
      float f = s_h[r][k];
      for (int j = 0; j < 16; ++j) acc[j] += f * s_w[k][n0 + j];
    }
    __syncthreads();               // all W2 + s_feat reads done
    for (int j = 0; j < 16; ++j) s_feat[r][n0 + j] = fmaxf(acc[j], 0.0f);
  }
  __syncthreads();

  // ---- layer 3, two 64-col halves, fused masked max-pool ----
  for (int h = 0; h < 2; ++h) {
    for (int idx = t; idx < 64 * 64; idx += 256)
      s_w[idx >> 6][idx & 63] = W3[(size_t)(idx >> 6) * 128 + h * 64 + (idx & 63)];
    __syncthreads();
    int n = t & 63, rg = t >> 6;
    float acc[16];
    float bias = b3[h * 64 + n];
    for (int rr = 0; rr < 16; ++rr) acc[rr] = bias;
    for (int k = 0; k < 64; ++k) {
      float w = s_w[k][n];
      for (int rr = 0; rr < 16; ++rr) acc[rr] += s_feat[rg * 16 + rr][k] * w;
    }
    float m = -__builtin_inff();
    for (int rr = 0; rr < 16; ++rr)
      m = fmaxf(m, fmaxf(acc[rr], 0.0f) + s_mask[rg * 16 + rr]);
    s_red[rg][n] = m;
    __syncthreads();
    if (t < 64) {
      float mm = fmaxf(fmaxf(s_red[0][t], s_red[1][t]), fmaxf(s_red[2][t], s_red[3][t]));
      out[(size_t)c * 128 + h * 64 + t] = mm;
    }
    __syncthreads();               // protect s_w restage for h=1
  }
}

// ---------------------------------------------------------------------------
extern "C" void kernel_launch(void* const* d_in, const int* in_sizes, int n_in,
                              void* d_out, int out_size, void* d_ws, size_t ws_size,
                              hipStream_t stream) {
  const float* x   = (const float*)d_in[0];
  const float* pos = (const float*)d_in[1];
  // d_in[2] = batch (int32), unused
  const float* W1 = (const float*)d_in[3];
  const float* b1 = (const float*)d_in[4];
  const float* W2 = (const float*)d_in[5];
  const float* b2 = (const float*)d_in[6];
  const float* W3 = (const float*)d_in[7];
  const float* b3 = (const float*)d_in[8];

  float* out = (float*)d_out;
  int* samp = (int*)d_ws;            // [8192]
  int* nbr = samp + BCL * MS;        // [8192*64]

  fps_kernel<<<BCL, 1024, 0, stream>>>(pos, samp, out);
  nbr_kernel<<<BCL * MS, 256, 0, stream>>>(pos, samp, nbr);
  mlp_kernel<<<BCL * MS, 256, 0, stream>>>(x, pos, samp, nbr,
                                           W1, b1, W2, b2, W3, b3, out);
}

// Round 5
// 3231.044 us; speedup vs baseline: 1.1406x; 1.0050x over previous
//
#include <hip/hip_runtime.h>

typedef unsigned short u16;
typedef unsigned int u32;
typedef unsigned long long u64;
typedef float f32x2 __attribute__((ext_vector_type(2)));

#define NPB 8192
#define BCL 4
#define MS 2048
#define KN 64
#define OFF_POS   (BCL * MS * 128)            // element offsets into d_out (f32)
#define OFF_BATCH (OFF_POS + BCL * MS * 3)

__device__ inline u64 umax64(u64 a, u64 b) { return a < b ? b : a; }

// packed f32 ops: IEEE-identical per half to v_add_f32 / v_mul_f32 -> bit-exact
__device__ inline f32x2 pk_add(f32x2 a, f32x2 b) {
  f32x2 d;
  asm("v_pk_add_f32 %0, %1, %2" : "=v"(d) : "v"(a), "v"(b));
  return d;
}
__device__ inline f32x2 pk_mul(f32x2 a, f32x2 b) {
  f32x2 d;
  asm("v_pk_mul_f32 %0, %1, %2" : "=v"(d) : "v"(a), "v"(b));
  return d;
}

// ---------------------------------------------------------------------------
// Kernel 1: farthest point sampling, one block/cloud, 1024 thr, 8 pts/thread
// (4 packed pairs). Exact f32 arithmetic (pk ops round identically to scalar),
// np argmax tie-break (first index) via key = (d2bits<<32)|~idx, u64 max.
// One barrier/iter; winner via single LDS atomicMax slot (triple-buffered).
// ---------------------------------------------------------------------------
__global__ __launch_bounds__(1024) void fps_kernel(
    const float* __restrict__ pos, int* __restrict__ samp,
    float* __restrict__ out) {
  int b = blockIdx.x, t = threadIdx.x;
  const float* pb = pos + (size_t)b * NPB * 3;

  __shared__ u64 slot[3];
  if (t < 3) slot[t] = 0;

  // pair j holds points (t + 2j*1024, t + (2j+1)*1024)
  f32x2 px[4], py[4], pz[4], mind[4];
  u32 lo[8];
  for (int j = 0; j < 4; ++j) {
    int pA = t + (2 * j) * 1024, pB = t + (2 * j + 1) * 1024;
    px[j] = f32x2{pb[pA * 3], pb[pB * 3]};
    py[j] = f32x2{pb[pA * 3 + 1], pb[pB * 3 + 1]};
    pz[j] = f32x2{pb[pA * 3 + 2], pb[pB * 3 + 2]};
    lo[2 * j] = ~(u32)pA;
    lo[2 * j + 1] = ~(u32)pB;
    mind[j] = f32x2{__builtin_inff(), __builtin_inff()};
  }
  float cx = pb[0], cy = pb[1], cz = pb[2];

  float* pos_out = out + OFF_POS + (size_t)b * MS * 3;
  float* batch_out = out + OFF_BATCH + (size_t)b * MS;
  if (t == 0) {
    samp[b * MS] = 0;
    pos_out[0] = cx; pos_out[1] = cy; pos_out[2] = cz;
  }
  // initial distances: min(+inf, d) == d exactly
  {
    f32x2 mcx = f32x2{-cx, -cx}, mcy = f32x2{-cy, -cy}, mcz = f32x2{-cz, -cz};
    #pragma unroll
    for (int j = 0; j < 4; ++j) {
      f32x2 dx = pk_add(px[j], mcx), dy = pk_add(py[j], mcy), dz = pk_add(pz[j], mcz);
      f32x2 d2 = pk_add(pk_add(pk_mul(dx, dx), pk_mul(dy, dy)), pk_mul(dz, dz));
      mind[j].x = fminf(mind[j].x, d2.x);
      mind[j].y = fminf(mind[j].y, d2.y);
    }
  }
  __syncthreads();   // slot[] zeroing + (no-op for regs)

  int cur = 1, nxt = 2;
  for (int it = 1; it < MS; ++it) {
    // keys: hi = d2 bits, lo = ~idx (loop-invariant regs)
    u64 k0 = ((u64)__float_as_uint(mind[0].x) << 32) | lo[0];
    u64 k1 = ((u64)__float_as_uint(mind[0].y) << 32) | lo[1];
    u64 k2 = ((u64)__float_as_uint(mind[1].x) << 32) | lo[2];
    u64 k3 = ((u64)__float_as_uint(mind[1].y) << 32) | lo[3];
    u64 k4 = ((u64)__float_as_uint(mind[2].x) << 32) | lo[4];
    u64 k5 = ((u64)__float_as_uint(mind[2].y) << 32) | lo[5];
    u64 k6 = ((u64)__float_as_uint(mind[3].x) << 32) | lo[6];
    u64 k7 = ((u64)__float_as_uint(mind[3].y) << 32) | lo[7];
    u64 best = umax64(umax64(umax64(k0, k1), umax64(k2, k3)),
                      umax64(umax64(k4, k5), umax64(k6, k7)));
    #pragma unroll
    for (int o = 32; o > 0; o >>= 1)
      best = umax64(best, __shfl_xor(best, o, 64));
    if ((t & 63) == 0) atomicMax((u64*)&slot[cur], best);
    if (t == 0) slot[nxt] = 0;     // zeroes the it+2 slot; 2 barriers separate reuse
    __syncthreads();
    u64 g = slot[cur];
    int win = (int)(~(u32)g) & (NPB - 1);
    // winner coords: uniform global load (L2-resident 96 KB cloud)
    cx = pb[win * 3]; cy = pb[win * 3 + 1]; cz = pb[win * 3 + 2];
    if (t == 0) {
      samp[b * MS + it] = win;
      pos_out[it * 3] = cx; pos_out[it * 3 + 1] = cy; pos_out[it * 3 + 2] = cz;
    }
    f32x2 mcx = f32x2{-cx, -cx}, mcy = f32x2{-cy, -cy}, mcz = f32x2{-cz, -cz};
    #pragma unroll
    for (int j = 0; j < 4; ++j) {
      f32x2 dx = pk_add(px[j], mcx), dy = pk_add(py[j], mcy), dz = pk_add(pz[j], mcz);
      f32x2 d2 = pk_add(pk_add(pk_mul(dx, dx), pk_mul(dy, dy)), pk_mul(dz, dz));
      mind[j].x = fminf(mind[j].x, d2.x);
      mind[j].y = fminf(mind[j].y, d2.y);
    }
    cur = nxt;
    nxt = nxt + 1 == 3 ? 0 : nxt + 1;
  }
  for (int m = t; m < MS; m += 1024) batch_out[m] = (float)b;
}

// ---------------------------------------------------------------------------
// Kernel 2: radius ball + K-nearest-in-ball (lax.top_k semantics). FROZEN (R4).
// ---------------------------------------------------------------------------
__global__ __launch_bounds__(256) void nbr_kernel(
    const float* __restrict__ pos, const int* __restrict__ samp,
    int* __restrict__ nbr) {
  const float R2CUT = (float)(0.2 * 0.2);   // 0x3D23D70A
  int c = blockIdx.x, b = c >> 11, t = threadIdx.x;
  const float* pb = pos + (size_t)b * NPB * 3;
  int s = samp[c] & (NPB - 1);
  float cx = pb[s * 3], cy = pb[s * 3 + 1], cz = pb[s * 3 + 2];
  __shared__ u64 cand[512];
  __shared__ int cnt;
  if (t == 0) cnt = 0;
  __syncthreads();
  for (int j = t; j < NPB; j += 256) {
    float dx = __fsub_rn(pb[j * 3], cx);
    float dy = __fsub_rn(pb[j * 3 + 1], cy);
    float dz = __fsub_rn(pb[j * 3 + 2], cz);
    float d2 = __fadd_rn(__fadd_rn(__fmul_rn(dx, dx), __fmul_rn(dy, dy)), __fmul_rn(dz, dz));
    if (d2 <= R2CUT) {
      int sl = atomicAdd(&cnt, 1);
      if (sl < 512) cand[sl] = ((u64)__float_as_uint(d2) << 32) | (u32)j;
    }
  }
  __syncthreads();
  int n = cnt; if (n > 512) n = 512;
  for (int i = t; i < 512; i += 256) if (i >= n) cand[i] = ~0ull;
  __syncthreads();
  for (int k = 2; k <= 512; k <<= 1) {
    for (int j = k >> 1; j > 0; j >>= 1) {
      for (int i = t; i < 512; i += 256) {
        int ix = i ^ j;
        if (ix > i) {
          u64 a = cand[i], bb = cand[ix];
          bool up = ((i & k) == 0);
          if ((a > bb) == up) { cand[i] = bb; cand[ix] = a; }
        }
      }
      __syncthreads();
    }
  }
  if (t < KN) nbr[(size_t)c * KN + t] = (t < n) ? (int)(cand[t] & 0xffffffffu) : -1;
}

// ---------------------------------------------------------------------------
// Kernel 3: gather -> f32 VALU MLP -> masked max-pool. FROZEN (R4, absmax 0.0).
// ---------------------------------------------------------------------------
__global__ __launch_bounds__(256) void mlp_kernel(
    const float* __restrict__ x, const float* __restrict__ pos,
    const int* __restrict__ samp, const int* __restrict__ nbr,
    const float* __restrict__ W1, const float* __restrict__ b1,
    const float* __restrict__ W2, const float* __restrict__ b2,
    const float* __restrict__ W3, const float* __restrict__ b3,
    float* __restrict__ out) {
  int c = blockIdx.x, b = c >> 11, t = threadIdx.x;

  __shared__ float s_feat[64][68];
  __shared__ float s_h[64][68];
  __shared__ float s_w[68][64];
  __shared__ float s_mask[64];
  __shared__ float s_red[4][64];

  const int* nb = nbr + (size_t)c * KN;

  {
    int r = t >> 2, q = t & 3;
    int j = nb[r];
    bool valid = (j >= 0 && j < NPB);
    size_t jj = valid ? (size_t)j : 0;
    const float4* xp = (const float4*)(x + ((size_t)b * NPB + jj) * 64 + q * 16);
    float4 v[4];
    for (int i = 0; i < 4; ++i) v[i] = xp[i];
    for (int i = 0; i < 4; ++i) {
      s_feat[r][q * 16 + i * 4 + 0] = valid ? v[i].x : 0.0f;
      s_feat[r][q * 16 + i * 4 + 1] = valid ? v[i].y : 0.0f;
      s_feat[r][q * 16 + i * 4 + 2] = valid ? v[i].z : 0.0f;
      s_feat[r][q * 16 + i * 4 + 3] = valid ? v[i].w : 0.0f;
    }
  }
  if (t < 64) {
    int r = t;
    int j = nb[r];
    bool valid = (j >= 0 && j < NPB);
    s_mask[r] = valid ? 0.0f : -__builtin_inff();
    int s = samp[c] & (NPB - 1);
    size_t jj = valid ? (size_t)j : (size_t)s;
    for (int d = 0; d < 3; ++d) {
      float pj = pos[((size_t)b * NPB + jj) * 3 + d];
      float pc = pos[((size_t)b * NPB + s) * 3 + d];
      s_feat[r][64 + d] = __fsub_rn(pj, pc);
    }
  }
  for (int idx = t; idx < 67 * 64; idx += 256)
    s_w[idx >> 6][idx & 63] = W1[idx];
  __syncthreads();

  {
    int r = t >> 2, n0 = (t & 3) * 16;
    float acc[16];
    for (int j = 0; j < 16; ++j) acc[j] = b1[n0 + j];
    for (int k = 0; k < 67; ++k) {
      float f = s_feat[r][k];
      for (int j = 0; j < 16; ++j) acc[j] += f * s_w[k][n0 + j];
    }
    __syncthreads();
    for (int j = 0; j < 16; ++j) s_h[r][n0 + j] = fmaxf(acc[j], 0.0f);
  }
  for (int idx = t; idx < 64 * 64; idx += 256)
    s_w[idx >> 6][idx & 63] = W2[idx];
  __syncthreads();

  {
    int r = t >> 2, n0 = (t & 3) * 16;
    float acc[16];
    for (int j = 0; j < 16; ++j) acc[j] = b2[n0 + j];
    for (int k = 0; k < 64; ++k) {
      float f = s_h[r][k];
      for (int j = 0; j < 16; ++j) acc[j] += f * s_w[k][n0 + j];
    }
    __syncthreads();
    for (int j = 0; j < 16; ++j) s_feat[r][n0 + j] = fmaxf(acc[j], 0.0f);
  }
  __syncthreads();

  for (int h = 0; h < 2; ++h) {
    for (int idx = t; idx < 64 * 64; idx += 256)
      s_w[idx >> 6][idx & 63] = W3[(size_t)(idx >> 6) * 128 + h * 64 + (idx & 63)];
    __syncthreads();
    int n = t & 63, rg = t >> 6;
    float acc[16];
    float bias = b3[h * 64 + n];
    for (int rr = 0; rr < 16; ++rr) acc[rr] = bias;
    for (int k = 0; k < 64; ++k) {
      float w = s_w[k][n];
      for (int rr = 0; rr < 16; ++rr) acc[rr] += s_feat[rg * 16 + rr][k] * w;
    }
    float m = -__builtin_inff();
    for (int rr = 0; rr < 16; ++rr)
      m = fmaxf(m, fmaxf(acc[rr], 0.0f) + s_mask[rg * 16 + rr]);
    s_red[rg][n] = m;
    __syncthreads();
    if (t < 64) {
      float mm = fmaxf(fmaxf(s_red[0][t], s_red[1][t]), fmaxf(s_red[2][t], s_red[3][t]));
      out[(size_t)c * 128 + h * 64 + t] = mm;
    }
    __syncthreads();
  }
}

// ---------------------------------------------------------------------------
extern "C" void kernel_launch(void* const* d_in, const int* in_sizes, int n_in,
                              void* d_out, int out_size, void* d_ws, size_t ws_size,
                              hipStream_t stream) {
  const float* x   = (const float*)d_in[0];
  const float* pos = (const float*)d_in[1];
  // d_in[2] = batch (int32), unused
  const float* W1 = (const float*)d_in[3];
  const float* b1 = (const float*)d_in[4];
  const float* W2 = (const float*)d_in[5];
  const float* b2 = (const float*)d_in[6];
  const float* W3 = (const float*)d_in[7];
  const float* b3 = (const float*)d_in[8];

  float* out = (float*)d_out;
  int* samp = (int*)d_ws;            // [8192]
  int* nbr = samp + BCL * MS;        // [8192*64]

  fps_kernel<<<BCL, 1024, 0, stream>>>(pos, samp, out);
  nbr_kernel<<<BCL * MS, 256, 0, stream>>>(pos, samp, nbr);
  mlp_kernel<<<BCL * MS, 256, 0, stream>>>(x, pos, samp, nbr,
                                           W1, b1, W2, b2, W3, b3, out);
}

// Round 6
// 2740.660 us; speedup vs baseline: 1.3447x; 1.1789x over previous
//
#include <hip/hip_runtime.h>

typedef unsigned int u32;
typedef unsigned long long u64;
typedef float f32x2 __attribute__((ext_vector_type(2)));

#define NPB 8192
#define BCL 4
#define MS 2048
#define KN 64
#define OFF_POS   (BCL * MS * 128)            // element offsets into d_out (f32)
#define OFF_BATCH (OFF_POS + BCL * MS * 3)

__device__ inline u64 umax64(u64 a, u64 b) { return a < b ? b : a; }

// packed f32 ops: IEEE-identical per half to v_add_f32 / v_mul_f32 -> bit-exact
__device__ inline f32x2 pk_add(f32x2 a, f32x2 b) {
  f32x2 d;
  asm("v_pk_add_f32 %0, %1, %2" : "=v"(d) : "v"(a), "v"(b));
  return d;
}
__device__ inline f32x2 pk_mul(f32x2 a, f32x2 b) {
  f32x2 d;
  asm("v_pk_mul_f32 %0, %1, %2" : "=v"(d) : "v"(a), "v"(b));
  return d;
}

__device__ inline u32 part1by2(u32 x) {   // spread 10 bits -> every 3rd bit
  x &= 0x3ffu;
  x = (x | (x << 16)) & 0x030000FFu;
  x = (x | (x << 8))  & 0x0300F00Fu;
  x = (x | (x << 4))  & 0x030C30C3u;
  x = (x | (x << 2))  & 0x09249249u;
  return x;
}

// ---------------------------------------------------------------------------
// Kernel 1: farthest point sampling with exact spatial pruning.
// One block/cloud, 1024 thr, 8 pts/thread. One-time Morton bitonic sort so
// each thread owns a spatially tight blob (wave = contiguous super-blob).
// Per iter: butterfly + single LDS atomicMax slot (R5 mechanism). The 8-pt
// distance update + key rebuild is SKIPPED when a conservative bbox lower
// bound proves (to 64-eps margin vs <=8-eps rounding slack) that no mind[]
// can change -> bit-exact vs the unpruned version (absmax 0.0 in R3-R5).
// Keys carry ORIGINAL indices: d2bits<<32 | ~idx (np argmax tie semantics).
// ---------------------------------------------------------------------------
__global__ __launch_bounds__(1024) void fps_kernel(
    const float* __restrict__ pos, int* __restrict__ samp,
    float* __restrict__ out) {
  extern __shared__ u64 smem[];   // 8192 u64 = 64 KB; reused: sort buf -> slots
  int b = blockIdx.x, t = threadIdx.x, lane = t & 63;
  const float* pb = pos + (size_t)b * NPB * 3;

  // ---- 1) Morton keys (30b) | orig idx (13b) ----
  for (int i = t; i < NPB; i += 1024) {
    float xx = pb[i * 3], yy = pb[i * 3 + 1], zz = pb[i * 3 + 2];
    u32 xi = (u32)fminf(fmaxf(xx * 1024.0f, 0.0f), 1023.0f);
    u32 yi = (u32)fminf(fmaxf(yy * 1024.0f, 0.0f), 1023.0f);
    u32 zi = (u32)fminf(fmaxf(zz * 1024.0f, 0.0f), 1023.0f);
    u32 m = (part1by2(zi) << 2) | (part1by2(yi) << 1) | part1by2(xi);
    smem[i] = ((u64)m << 13) | (u32)i;
  }
  // ---- 2) bitonic sort 8192 ----
  for (int k = 2; k <= NPB; k <<= 1) {
    for (int j = k >> 1; j > 0; j >>= 1) {
      __syncthreads();
      for (int i = t; i < NPB; i += 1024) {
        int ix = i ^ j;
        if (ix > i) {
          u64 a = smem[i], c = smem[ix];
          bool up = ((i & k) == 0);
          if ((a > c) == up) { smem[i] = c; smem[ix] = a; }
        }
      }
    }
  }
  __syncthreads();
  // ---- 3) extract my blob (8 consecutive sorted points) ----
  int oi[8];
  #pragma unroll
  for (int i = 0; i < 8; ++i) oi[i] = (int)(smem[8 * t + i] & 0x1FFFu);
  __syncthreads();                 // sort data dead; smem[0..2] become slots
  if (t < 3) smem[t] = 0;

  // gather coords (one-time scattered, L2-hot) + bbox + tie-break lo words
  f32x2 px[4], py[4], pz[4], mind[4];
  u32 lo[8];
  float bxl = 1e30f, bxh = -1e30f, byl = 1e30f, byh = -1e30f, bzl = 1e30f, bzh = -1e30f;
  #pragma unroll
  for (int j = 0; j < 4; ++j) {
    int iA = oi[2 * j], iB = oi[2 * j + 1];
    float xA = pb[iA * 3], yA = pb[iA * 3 + 1], zA = pb[iA * 3 + 2];
    float xB = pb[iB * 3], yB = pb[iB * 3 + 1], zB = pb[iB * 3 + 2];
    px[j] = f32x2{xA, xB}; py[j] = f32x2{yA, yB}; pz[j] = f32x2{zA, zB};
    lo[2 * j] = ~(u32)iA; lo[2 * j + 1] = ~(u32)iB;
    bxl = fminf(bxl, fminf(xA, xB)); bxh = fmaxf(bxh, fmaxf(xA, xB));
    byl = fminf(byl, fminf(yA, yB)); byh = fmaxf(byh, fmaxf(yA, yB));
    bzl = fminf(bzl, fminf(zA, zB)); bzh = fmaxf(bzh, fmaxf(zA, zB));
  }

  // ---- 4) init distances vs point 0 + initial best key ----
  float cx = pb[0], cy = pb[1], cz = pb[2];
  float* pos_out = out + OFF_POS + (size_t)b * MS * 3;
  float* batch_out = out + OFF_BATCH + (size_t)b * MS;
  if (t == 0) {
    samp[b * MS] = 0;
    pos_out[0] = cx; pos_out[1] = cy; pos_out[2] = cz;
  }
  u64 lkey;
  {
    f32x2 mcx = f32x2{-cx, -cx}, mcy = f32x2{-cy, -cy}, mcz = f32x2{-cz, -cz};
    #pragma unroll
    for (int j = 0; j < 4; ++j) {
      f32x2 dx = pk_add(px[j], mcx), dy = pk_add(py[j], mcy), dz = pk_add(pz[j], mcz);
      mind[j] = pk_add(pk_add(pk_mul(dx, dx), pk_mul(dy, dy)), pk_mul(dz, dz));
    }
    u64 k0 = ((u64)__float_as_uint(mind[0].x) << 32) | lo[0];
    u64 k1 = ((u64)__float_as_uint(mind[0].y) << 32) | lo[1];
    u64 k2 = ((u64)__float_as_uint(mind[1].x) << 32) | lo[2];
    u64 k3 = ((u64)__float_as_uint(mind[1].y) << 32) | lo[3];
    u64 k4 = ((u64)__float_as_uint(mind[2].x) << 32) | lo[4];
    u64 k5 = ((u64)__float_as_uint(mind[2].y) << 32) | lo[5];
    u64 k6 = ((u64)__float_as_uint(mind[3].x) << 32) | lo[6];
    u64 k7 = ((u64)__float_as_uint(mind[3].y) << 32) | lo[7];
    lkey = umax64(umax64(umax64(k0, k1), umax64(k2, k3)),
                  umax64(umax64(k4, k5), umax64(k6, k7)));
  }
  __syncthreads();                 // slots zeroed, everyone initialized

  int cur = 1, nxt = 2;
  for (int it = 1; it < MS; ++it) {
    // block argmax: wave butterfly on cached lkey + one LDS atomicMax slot
    u64 best = lkey;
    #pragma unroll
    for (int o = 32; o > 0; o >>= 1)
      best = umax64(best, __shfl_xor(best, o, 64));
    if (lane == 0) atomicMax((u64*)&smem[cur], best);
    if (t == 0) smem[nxt] = 0;     // zero the it+2 slot (2 barriers before reuse)
    __syncthreads();
    u64 g = smem[cur];
    int win = (int)(~(u32)g) & (NPB - 1);
    float ncx = pb[win * 3], ncy = pb[win * 3 + 1], ncz = pb[win * 3 + 2];
    if (t == 0) {
      samp[b * MS + it] = win;
      pos_out[it * 3] = ncx; pos_out[it * 3 + 1] = ncy; pos_out[it * 3 + 2] = ncz;
    }
    // exact-skip test: conservative bbox lower bound vs cached blob max
    float lmax = __uint_as_float((u32)(lkey >> 32));
    float ax = fmaxf(fmaxf(__fsub_rn(bxl, ncx), __fsub_rn(ncx, bxh)), 0.0f);
    float ay = fmaxf(fmaxf(__fsub_rn(byl, ncy), __fsub_rn(ncy, byh)), 0.0f);
    float az = fmaxf(fmaxf(__fsub_rn(bzl, ncz), __fsub_rn(ncz, bzh)), 0.0f);
    float lb2 = (ax * ax + ay * ay + az * az) * 0.9999961853f;  // *(1-2^-18)
    if (lb2 <= lmax) {             // blob may change: do the exact update
      f32x2 mcx = f32x2{-ncx, -ncx}, mcy = f32x2{-ncy, -ncy}, mcz = f32x2{-ncz, -ncz};
      #pragma unroll
      for (int j = 0; j < 4; ++j) {
        f32x2 dx = pk_add(px[j], mcx), dy = pk_add(py[j], mcy), dz = pk_add(pz[j], mcz);
        f32x2 d2 = pk_add(pk_add(pk_mul(dx, dx), pk_mul(dy, dy)), pk_mul(dz, dz));
        mind[j].x = fminf(mind[j].x, d2.x);
        mind[j].y = fminf(mind[j].y, d2.y);
      }
      u64 k0 = ((u64)__float_as_uint(mind[0].x) << 32) | lo[0];
      u64 k1 = ((u64)__float_as_uint(mind[0].y) << 32) | lo[1];
      u64 k2 = ((u64)__float_as_uint(mind[1].x) << 32) | lo[2];
      u64 k3 = ((u64)__float_as_uint(mind[1].y) << 32) | lo[3];
      u64 k4 = ((u64)__float_as_uint(mind[2].x) << 32) | lo[4];
      u64 k5 = ((u64)__float_as_uint(mind[2].y) << 32) | lo[5];
      u64 k6 = ((u64)__float_as_uint(mind[3].x) << 32) | lo[6];
      u64 k7 = ((u64)__float_as_uint(mind[3].y) << 32) | lo[7];
      lkey = umax64(umax64(umax64(k0, k1), umax64(k2, k3)),
                    umax64(umax64(k4, k5), umax64(k6, k7)));
    }
    cur = nxt;
    nxt = nxt + 1 == 3 ? 0 : nxt + 1;
  }
  for (int m = t; m < MS; m += 1024) batch_out[m] = (float)b;
}

// ---------------------------------------------------------------------------
// Kernel 2: radius ball + K-nearest-in-ball (lax.top_k semantics). FROZEN.
// ---------------------------------------------------------------------------
__global__ __launch_bounds__(256) void nbr_kernel(
    const float* __restrict__ pos, const int* __restrict__ samp,
    int* __restrict__ nbr) {
  const float R2CUT = (float)(0.2 * 0.2);   // 0x3D23D70A
  int c = blockIdx.x, b = c >> 11, t = threadIdx.x;
  const float* pb = pos + (size_t)b * NPB * 3;
  int s = samp[c] & (NPB - 1);
  float cx = pb[s * 3], cy = pb[s * 3 + 1], cz = pb[s * 3 + 2];
  __shared__ u64 cand[512];
  __shared__ int cnt;
  if (t == 0) cnt = 0;
  __syncthreads();
  for (int j = t; j < NPB; j += 256) {
    float dx = __fsub_rn(pb[j * 3], cx);
    float dy = __fsub_rn(pb[j * 3 + 1], cy);
    float dz = __fsub_rn(pb[j * 3 + 2], cz);
    float d2 = __fadd_rn(__fadd_rn(__fmul_rn(dx, dx), __fmul_rn(dy, dy)), __fmul_rn(dz, dz));
    if (d2 <= R2CUT) {
      int sl = atomicAdd(&cnt, 1);
      if (sl < 512) cand[sl] = ((u64)__float_as_uint(d2) << 32) | (u32)j;
    }
  }
  __syncthreads();
  int n = cnt; if (n > 512) n = 512;
  for (int i = t; i < 512; i += 256) if (i >= n) cand[i] = ~0ull;
  __syncthreads();
  for (int k = 2; k <= 512; k <<= 1) {
    for (int j = k >> 1; j > 0; j >>= 1) {
      for (int i = t; i < 512; i += 256) {
        int ix = i ^ j;
        if (ix > i) {
          u64 a = cand[i], bb = cand[ix];
          bool up = ((i & k) == 0);
          if ((a > bb) == up) { cand[i] = bb; cand[ix] = a; }
        }
      }
      __syncthreads();
    }
  }
  if (t < KN) nbr[(size_t)c * KN + t] = (t < n) ? (int)(cand[t] & 0xffffffffu) : -1;
}

// ---------------------------------------------------------------------------
// Kernel 3: gather -> f32 VALU MLP -> masked max-pool. FROZEN (absmax 0.0).
// ---------------------------------------------------------------------------
__global__ __launch_bounds__(256) void mlp_kernel(
    const float* __restrict__ x, const float* __restrict__ pos,
    const int* __restrict__ samp, const int* __restrict__ nbr,
    const float* __restrict__ W1, const float* __restrict__ b1,
    const float* __restrict__ W2, const float* __restrict__ b2,
    const float* __restrict__ W3, const float* __restrict__ b3,
    float* __restrict__ out) {
  int c = blockIdx.x, b = c >> 11, t = threadIdx.x;

  __shared__ float s_feat[64][68];
  __shared__ float s_h[64][68];
  __shared__ float s_w[68][64];
  __shared__ float s_mask[64];
  __shared__ float s_red[4][64];

  const int* nb = nbr + (size_t)c * KN;

  {
    int r = t >> 2, q = t & 3;
    int j = nb[r];
    bool valid = (j >= 0 && j < NPB);
    size_t jj = valid ? (size_t)j : 0;
    const float4* xp = (const float4*)(x + ((size_t)b * NPB + jj) * 64 + q * 16);
    float4 v[4];
    for (int i = 0; i < 4; ++i) v[i] = xp[i];
    for (int i = 0; i < 4; ++i) {
      s_feat[r][q * 16 + i * 4 + 0] = valid ? v[i].x : 0.0f;
      s_feat[r][q * 16 + i * 4 + 1] = valid ? v[i].y : 0.0f;
      s_feat[r][q * 16 + i * 4 + 2] = valid ? v[i].z : 0.0f;
      s_feat[r][q * 16 + i * 4 + 3] = valid ? v[i].w : 0.0f;
    }
  }
  if (t < 64) {
    int r = t;
    int j = nb[r];
    bool valid = (j >= 0 && j < NPB);
    s_mask[r] = valid ? 0.0f : -__builtin_inff();
    int s = samp[c] & (NPB - 1);
    size_t jj = valid ? (size_t)j : (size_t)s;
    for (int d = 0; d < 3; ++d) {
      float pj = pos[((size_t)b * NPB + jj) * 3 + d];
      float pc = pos[((size_t)b * NPB + s) * 3 + d];
      s_feat[r][64 + d] = __fsub_rn(pj, pc);
    }
  }
  for (int idx = t; idx < 67 * 64; idx += 256)
    s_w[idx >> 6][idx & 63] = W1[idx];
  __syncthreads();

  {
    int r = t >> 2, n0 = (t & 3) * 16;
    float acc[16];
    for (int j = 0; j < 16; ++j) acc[j] = b1[n0 + j];
    for (int k = 0; k < 67; ++k) {
      float f = s_feat[r][k];
      for (int j = 0; j < 16; ++j) acc[j] += f * s_w[k][n0 + j];
    }
    __syncthreads();
    for (int j = 0; j < 16; ++j) s_h[r][n0 + j] = fmaxf(acc[j], 0.0f);
  }
  for (int idx = t; idx < 64 * 64; idx += 256)
    s_w[idx >> 6][idx & 63] = W2[idx];
  __syncthreads();

  {
    int r = t >> 2, n0 = (t & 3) * 16;
    float acc[16];
    for (int j = 0; j < 16; ++j) acc[j] = b2[n0 + j];
    for (int k = 0; k < 64; ++k) {
      float f = s_h[r][k];
      for (int j = 0; j < 16; ++j) acc[j] += f * s_w[k][n0 + j];
    }
    __syncthreads();
    for (int j = 0; j < 16; ++j) s_feat[r][n0 + j] = fmaxf(acc[j], 0.0f);
  }
  __syncthreads();

  for (int h = 0; h < 2; ++h) {
    for (int idx = t; idx < 64 * 64; idx += 256)
      s_w[idx >> 6][idx & 63] = W3[(size_t)(idx >> 6) * 128 + h * 64 + (idx & 63)];
    __syncthreads();
    int n = t & 63, rg = t >> 6;
    float acc[16];
    float bias = b3[h * 64 + n];
    for (int rr = 0; rr < 16; ++rr) acc[rr] = bias;
    for (int k = 0; k < 64; ++k) {
      float w = s_w[k][n];
      for (int rr = 0; rr < 16; ++rr) acc[rr] += s_feat[rg * 16 + rr][k] * w;
    }
    float m = -__builtin_inff();
    for (int rr = 0; rr < 16; ++rr)
      m = fmaxf(m, fmaxf(acc[rr], 0.0f) + s_mask[rg * 16 + rr]);
    s_red[rg][n] = m;
    __syncthreads();
    if (t < 64) {
      float mm = fmaxf(fmaxf(s_red[0][t], s_red[1][t]), fmaxf(s_red[2][t], s_red[3][t]));
      out[(size_t)c * 128 + h * 64 + t] = mm;
    }
    __syncthreads();
  }
}

// ---------------------------------------------------------------------------
extern "C" void kernel_launch(void* const* d_in, const int* in_sizes, int n_in,
                              void* d_out, int out_size, void* d_ws, size_t ws_size,
                              hipStream_t stream) {
  const float* x   = (const float*)d_in[0];
  const float* pos = (const float*)d_in[1];
  // d_in[2] = batch (int32), unused
  const float* W1 = (const float*)d_in[3];
  const float* b1 = (const float*)d_in[4];
  const float* W2 = (const float*)d_in[5];
  const float* b2 = (const float*)d_in[6];
  const float* W3 = (const float*)d_in[7];
  const float* b3 = (const float*)d_in[8];

  float* out = (float*)d_out;
  int* samp = (int*)d_ws;            // [8192]
  int* nbr = samp + BCL * MS;        // [8192*64]

  fps_kernel<<<BCL, 1024, NPB * sizeof(u64), stream>>>(pos, samp, out);
  nbr_kernel<<<BCL * MS, 256, 0, stream>>>(pos, samp, nbr);
  mlp_kernel<<<BCL * MS, 256, 0, stream>>>(x, pos, samp, nbr,
                                           W1, b1, W2, b2, W3, b3, out);
}